// Round 3
// baseline (762.464 us; speedup 1.0000x reference)
//
#include <hip/hip_runtime.h>
#include <hip/hip_bf16.h>

#define NB 8
#define LSEQ 2048
#define HH 8
#define DD 32
#define EE 256
#define NE 32
#define QT 16      // queries per block (one MFMA tile of rows)
#define NWAVE 8
#define NTH 512
#define KW 256     // keys per wave
#define NTILE 16   // KW / 16
#define SMS 2050   // smean row stride (words): 4-row groups land on distinct bank octets

typedef __attribute__((ext_vector_type(8))) short short8;
typedef __attribute__((ext_vector_type(4))) float f32x4;

// ---------------------------------------------------------------------------
// K1: per-head projection -> 3-way bf16 split (hi/mid/lo ~ 24 mantissa bits).
// out[n][h][l][e] = scale * sum_d x[n][l][h*32+d] * W[e*32+d]
// Q pass uses scale = 1/16 (exact power of two; folds softmax temperature).
// ---------------------------------------------------------------------------
__global__ __launch_bounds__(256) void proj_kernel(const float* __restrict__ x,
                                                   const float* __restrict__ W,
                                                   float scale,
                                                   __hip_bfloat16* __restrict__ o1,
                                                   __hip_bfloat16* __restrict__ o2,
                                                   __hip_bfloat16* __restrict__ o3) {
  const int b = blockIdx.x;  // n*L + l
  __shared__ float xs[EE];
  __shared__ float Ws[DD][DD + 1];
  const int t = threadIdx.x;
  xs[t] = x[(size_t)b * EE + t];
  for (int i = t; i < DD * DD; i += 256) Ws[i / DD][i % DD] = W[i];
  __syncthreads();
  const int h = t / DD, e = t % DD;
  float acc = 0.f;
#pragma unroll
  for (int d = 0; d < DD; ++d) acc = fmaf(xs[h * DD + d], Ws[e][d], acc);
  acc *= scale;
  const int n = b / LSEQ, l = b % LSEQ;
  const size_t oi = (((size_t)n * HH + h) * LSEQ + l) * DD + e;
  __hip_bfloat16 p1 = __float2bfloat16(acc);
  float r1 = acc - __bfloat162float(p1);
  __hip_bfloat16 p2 = __float2bfloat16(r1);
  float r2 = r1 - __bfloat162float(p2);
  __hip_bfloat16 p3 = __float2bfloat16(r2);
  o1[oi] = p1;
  o2[oi] = p2;
  o3[oi] = p3;
}

// ---------------------------------------------------------------------------
// K2: MFMA energy -> per-head softmax (no max-sub; energies/16 bounded ~±3)
//     -> mean accumulated in REGISTERS -> two-pass LDS redistribute -> top-32.
// One block = (n, 16-query tile). 8 waves; wave w owns keys [w*256,(w+1)*256).
// C fragment mapping (verified round 2): row(query)=g*4+r, col(key)=c.
// ---------------------------------------------------------------------------
__global__ __launch_bounds__(NTH, 4) void attn_topk_kernel(
    const __hip_bfloat16* __restrict__ q1, const __hip_bfloat16* __restrict__ q2,
    const __hip_bfloat16* __restrict__ q3, const __hip_bfloat16* __restrict__ k1,
    const __hip_bfloat16* __restrict__ k2, const __hip_bfloat16* __restrict__ k3,
    int* __restrict__ out) {
  __shared__ float smean[8 * SMS];        // 65.6 KB: 8 query rows per pass
  __shared__ float wredS[2][QT][NWAVE];   // cross-wave Z partials, dbuf by head parity

  const int t = threadIdx.x;
  const int w = t >> 6, l = t & 63;
  const int g = l >> 4, c = l & 15;  // 16-lane group / lane-in-group
  const int n = blockIdx.x & 7;      // XCD-aligned batch (1024 blocks, %8==0: bijective)
  const int q0 = (blockIdx.x >> 3) * QT;

  float macc[NTILE][4];  // mean-attn accumulator: rows g*4+r, cols w*256+t2*16+c
#pragma unroll
  for (int t2 = 0; t2 < NTILE; ++t2)
#pragma unroll
    for (int r = 0; r < 4; ++r) macc[t2][r] = 0.f;

  for (int h = 0; h < HH; ++h) {
    const size_t hb = ((size_t)n * HH + h) * LSEQ;
    // A fragment (Q): row = c, d-range = g*8..g*8+7
    const size_t qoff = (hb + q0 + c) * DD + (size_t)g * 8;
    const short8 aH = *(const short8*)(q1 + qoff);
    const short8 aM = *(const short8*)(q2 + qoff);
    const short8 aL = *(const short8*)(q3 + qoff);

    f32x4 acc[NTILE];
#pragma unroll
    for (int t2 = 0; t2 < NTILE; ++t2) {
      // B fragment (K): col = c, d-range = g*8..g*8+7
      const size_t koff = (hb + (size_t)w * KW + t2 * 16 + c) * DD + (size_t)g * 8;
      const short8 bH = *(const short8*)(k1 + koff);
      const short8 bM = *(const short8*)(k2 + koff);
      const short8 bL = *(const short8*)(k3 + koff);
      f32x4 a = {0.f, 0.f, 0.f, 0.f};
      a = __builtin_amdgcn_mfma_f32_16x16x32_bf16(aH, bH, a, 0, 0, 0);
      a = __builtin_amdgcn_mfma_f32_16x16x32_bf16(aH, bM, a, 0, 0, 0);
      a = __builtin_amdgcn_mfma_f32_16x16x32_bf16(aM, bH, a, 0, 0, 0);
      a = __builtin_amdgcn_mfma_f32_16x16x32_bf16(aH, bL, a, 0, 0, 0);
      a = __builtin_amdgcn_mfma_f32_16x16x32_bf16(aL, bH, a, 0, 0, 0);
      a = __builtin_amdgcn_mfma_f32_16x16x32_bf16(aM, bM, a, 0, 0, 0);
      acc[t2] = a;
    }

    // --- exp (energies pre-scaled by 1/16 in Q proj; bounded, no max-sub) + Z ---
    float Zl[4] = {0.f, 0.f, 0.f, 0.f};
#pragma unroll
    for (int t2 = 0; t2 < NTILE; ++t2) {
#pragma unroll
      for (int r = 0; r < 4; ++r) {
        float e = __expf(acc[t2][r]);
        acc[t2][r] = e;
        Zl[r] += e;
      }
    }
#pragma unroll
    for (int msk = 1; msk <= 8; msk <<= 1)
#pragma unroll
      for (int r = 0; r < 4; ++r) Zl[r] += __shfl_xor(Zl[r], msk);
    if (c == 0) {
#pragma unroll
      for (int r = 0; r < 4; ++r) wredS[h & 1][g * 4 + r][w] = Zl[r];
    }
    __syncthreads();
    float inv[4];
#pragma unroll
    for (int r = 0; r < 4; ++r) {
      float z = wredS[h & 1][g * 4 + r][c & 7];
#pragma unroll
      for (int msk = 1; msk <= 4; msk <<= 1) z += __shfl_xor(z, msk);
      inv[r] = __builtin_amdgcn_rcpf(z);  // per-row monotone scale: order-safe
    }
    // --- accumulate mean rows in registers (mean /8 monotone: skip) ---
#pragma unroll
    for (int t2 = 0; t2 < NTILE; ++t2)
#pragma unroll
      for (int r = 0; r < 4; ++r) macc[t2][r] = fmaf(acc[t2][r], inv[r], macc[t2][r]);
  }

  // --- two passes: redistribute 8 rows to LDS, then per-wave top-32 ---
  for (int pass = 0; pass < 2; ++pass) {
    if (pass) __syncthreads();  // protect smean reuse (pass-0 reads done)
    if ((g >> 1) == pass) {
#pragma unroll
      for (int t2 = 0; t2 < NTILE; ++t2)
#pragma unroll
        for (int r = 0; r < 4; ++r)
          smean[((g & 1) * 4 + r) * SMS + w * KW + t2 * 16 + c] = macc[t2][r];
    }
    __syncthreads();

    // wave w: top-32 of local row w (query q0 + pass*8 + w); k = j*64 + l
    float* row = &smean[w * SMS];
    float vals[32];
    float v1 = -1e30f, v2 = -1e30f;
    int i1 = 1 << 30, i2 = 1 << 30;
#pragma unroll
    for (int j = 0; j < 32; ++j) {
      float v = row[j * 64 + l];
      vals[j] = v;
      const int k = j * 64 + l;
      if (v > v1) { v2 = v1; i2 = i1; v1 = v; i1 = k; }
      else if (v > v2) { v2 = v; i2 = k; }
    }
    unsigned rem = 0u;
    int selk = 0;
#pragma unroll 1
    for (int it = 0; it < NE; ++it) {
      float bv = v1;
      int bk = i1;
#pragma unroll
      for (int off = 32; off >= 1; off >>= 1) {
        float ov = __shfl_xor(bv, off);
        int ok = __shfl_xor(bk, off);
        if (ov > bv || (ov == bv && ok < bk)) { bv = ov; bk = ok; }
      }
      if (l == it) selk = bk;
      if (i1 == bk) {  // this lane supplied the winner (k%64==l: unique owner)
        rem |= 1u << (bk >> 6);
        if (i2 != (1 << 30)) {  // promote cached second
          v1 = v2; i1 = i2;
          v2 = -1e30f; i2 = 1 << 30;
        } else {  // rare: rebuild top-2 from masked registers
          v1 = -1e30f; i1 = 1 << 30;
          v2 = -1e30f; i2 = 1 << 30;
#pragma unroll
          for (int j = 0; j < 32; ++j) {
            float v = ((rem >> j) & 1u) ? -1e30f : vals[j];
            const int k = j * 64 + l;
            if (v > v1) { v2 = v1; i2 = i1; v1 = v; i1 = k; }
            else if (v > v2) { v2 = v; i2 = k; }
          }
        }
      }
    }

    // rank-sort the 32 winners by index, write output
    int rank = 0;
#pragma unroll
    for (int j = 0; j < NE; ++j) {
      int o = __shfl(selk, j);
      rank += (o < selk) ? 1 : 0;
    }
    const int qg = q0 + pass * 8 + w;
    if (l < NE) {
      int* o0 = out + (size_t)n * 2 * LSEQ * NE + (size_t)qg * NE;
      int* o1p = o0 + (size_t)LSEQ * NE;
      o0[l] = qg;
      o1p[rank] = selk;
    }
  }
}

// ---------------------------------------------------------------------------
extern "C" void kernel_launch(void* const* d_in, const int* in_sizes, int n_in,
                              void* d_out, int out_size, void* d_ws, size_t ws_size,
                              hipStream_t stream) {
  const float* keys = (const float*)d_in[0];
  const float* query = (const float*)d_in[1];
  const float* Wk = (const float*)d_in[2];
  const float* Wq = (const float*)d_in[3];
  int* out = (int*)d_out;

  const size_t SPLIT = (size_t)NB * HH * LSEQ * DD;  // 4,194,304 elems
  __hip_bfloat16* qs1 = (__hip_bfloat16*)d_ws;
  __hip_bfloat16* qs2 = qs1 + SPLIT;
  __hip_bfloat16* qs3 = qs2 + SPLIT;
  __hip_bfloat16* ks1 = qs3 + SPLIT;
  __hip_bfloat16* ks2 = ks1 + SPLIT;
  __hip_bfloat16* ks3 = ks2 + SPLIT;

  proj_kernel<<<NB * LSEQ, 256, 0, stream>>>(query, Wq, 0.0625f, qs1, qs2, qs3);
  proj_kernel<<<NB * LSEQ, 256, 0, stream>>>(keys, Wk, 1.0f, ks1, ks2, ks3);
  attn_topk_kernel<<<NB * (LSEQ / QT), NTH, 0, stream>>>(qs1, qs2, qs3, ks1, ks2, ks3, out);
}

// Round 4
// 556.841 us; speedup vs baseline: 1.3693x; 1.3693x over previous
//
#include <hip/hip_runtime.h>
#include <hip/hip_bf16.h>

#define NB 8
#define LSEQ 2048
#define HH 8
#define DD 32
#define EE 256
#define NE 32
#define QT 16      // queries per block (one MFMA tile of rows)
#define NWAVE 8
#define NTH 512
#define KW 256     // keys per wave
#define NTILE 16   // KW / 16
#define SMS 2050   // smean row stride (words)

typedef __attribute__((ext_vector_type(8))) short short8;
typedef __attribute__((ext_vector_type(4))) float f32x4;

// ---------------------------------------------------------------------------
// K1: per-head projection -> 3-way bf16 split (hi/mid/lo ~ 24 mantissa bits).
// out[n][h][l][e] = scale * sum_d x[n][l][h*32+d] * W[e*32+d]
// Q pass uses scale = 1/16 (exact power of two; folds softmax temperature).
// ---------------------------------------------------------------------------
__global__ __launch_bounds__(256) void proj_kernel(const float* __restrict__ x,
                                                   const float* __restrict__ W,
                                                   float scale,
                                                   __hip_bfloat16* __restrict__ o1,
                                                   __hip_bfloat16* __restrict__ o2,
                                                   __hip_bfloat16* __restrict__ o3) {
  const int b = blockIdx.x;  // n*L + l
  __shared__ float xs[EE];
  __shared__ float Ws[DD][DD + 1];
  const int t = threadIdx.x;
  xs[t] = x[(size_t)b * EE + t];
  for (int i = t; i < DD * DD; i += 256) Ws[i / DD][i % DD] = W[i];
  __syncthreads();
  const int h = t / DD, e = t % DD;
  float acc = 0.f;
#pragma unroll
  for (int d = 0; d < DD; ++d) acc = fmaf(xs[h * DD + d], Ws[e][d], acc);
  acc *= scale;
  const int n = b / LSEQ, l = b % LSEQ;
  const size_t oi = (((size_t)n * HH + h) * LSEQ + l) * DD + e;
  __hip_bfloat16 p1 = __float2bfloat16(acc);
  float r1 = acc - __bfloat162float(p1);
  __hip_bfloat16 p2 = __float2bfloat16(r1);
  float r2 = r1 - __bfloat162float(p2);
  __hip_bfloat16 p3 = __float2bfloat16(r2);
  o1[oi] = p1;
  o2[oi] = p2;
  o3[oi] = p3;
}

// ---------------------------------------------------------------------------
// K2: MFMA energy -> per-head softmax (no max-sub; energies/16 bounded ~±3)
//     -> mean accumulated in REGISTERS -> two-pass LDS redistribute -> top-32.
// One block = (n, 16-query tile). 8 waves; wave w owns keys [w*256,(w+1)*256).
// __launch_bounds__(512, 2): 256-VGPR cap so macc+acc (~160 live) do NOT spill.
// C fragment mapping (verified rounds 2-3): row(query)=g*4+r, col(key)=c.
// ---------------------------------------------------------------------------
__global__ __launch_bounds__(NTH, 2) void attn_topk_kernel(
    const __hip_bfloat16* __restrict__ q1, const __hip_bfloat16* __restrict__ q2,
    const __hip_bfloat16* __restrict__ q3, const __hip_bfloat16* __restrict__ k1,
    const __hip_bfloat16* __restrict__ k2, const __hip_bfloat16* __restrict__ k3,
    int* __restrict__ out) {
  __shared__ float smean[8 * SMS];        // 65.6 KB: 8 query rows per pass
  __shared__ float wredS[2][QT][NWAVE];   // cross-wave Z partials, dbuf by head parity

  const int t = threadIdx.x;
  const int w = t >> 6, l = t & 63;
  const int g = l >> 4, c = l & 15;  // 16-lane group / lane-in-group
  const int n = blockIdx.x & 7;      // XCD-aligned batch (1024 blocks, %8==0: bijective)
  const int q0 = (blockIdx.x >> 3) * QT;

  float macc[NTILE][4];  // mean-attn accumulator: rows g*4+r, cols w*256+t2*16+c
#pragma unroll
  for (int t2 = 0; t2 < NTILE; ++t2)
#pragma unroll
    for (int r = 0; r < 4; ++r) macc[t2][r] = 0.f;

  for (int h = 0; h < HH; ++h) {
    const size_t hb = ((size_t)n * HH + h) * LSEQ;
    // A fragment (Q): row = c, d-range = g*8..g*8+7
    const size_t qoff = (hb + q0 + c) * DD + (size_t)g * 8;
    const short8 aH = *(const short8*)(q1 + qoff);
    const short8 aM = *(const short8*)(q2 + qoff);
    const short8 aL = *(const short8*)(q3 + qoff);

    f32x4 acc[NTILE];
#pragma unroll
    for (int t2 = 0; t2 < NTILE; ++t2) {
      // B fragment (K): col = c, d-range = g*8..g*8+7
      const size_t koff = (hb + (size_t)w * KW + t2 * 16 + c) * DD + (size_t)g * 8;
      const short8 bH = *(const short8*)(k1 + koff);
      const short8 bM = *(const short8*)(k2 + koff);
      const short8 bL = *(const short8*)(k3 + koff);
      f32x4 a = {0.f, 0.f, 0.f, 0.f};
      a = __builtin_amdgcn_mfma_f32_16x16x32_bf16(aH, bH, a, 0, 0, 0);
      a = __builtin_amdgcn_mfma_f32_16x16x32_bf16(aH, bM, a, 0, 0, 0);
      a = __builtin_amdgcn_mfma_f32_16x16x32_bf16(aM, bH, a, 0, 0, 0);
      a = __builtin_amdgcn_mfma_f32_16x16x32_bf16(aH, bL, a, 0, 0, 0);
      a = __builtin_amdgcn_mfma_f32_16x16x32_bf16(aL, bH, a, 0, 0, 0);
      a = __builtin_amdgcn_mfma_f32_16x16x32_bf16(aM, bM, a, 0, 0, 0);
      acc[t2] = a;
    }

    // --- exp (energies pre-scaled by 1/16 in Q proj; bounded, no max-sub) + Z ---
    float Zl[4] = {0.f, 0.f, 0.f, 0.f};
#pragma unroll
    for (int t2 = 0; t2 < NTILE; ++t2) {
#pragma unroll
      for (int r = 0; r < 4; ++r) {
        float e = __expf(acc[t2][r]);
        acc[t2][r] = e;
        Zl[r] += e;
      }
    }
#pragma unroll
    for (int msk = 1; msk <= 8; msk <<= 1)
#pragma unroll
      for (int r = 0; r < 4; ++r) Zl[r] += __shfl_xor(Zl[r], msk);
    if (c == 0) {
#pragma unroll
      for (int r = 0; r < 4; ++r) wredS[h & 1][g * 4 + r][w] = Zl[r];
    }
    __syncthreads();
    float inv[4];
#pragma unroll
    for (int r = 0; r < 4; ++r) {
      float z = wredS[h & 1][g * 4 + r][c & 7];
#pragma unroll
      for (int msk = 1; msk <= 4; msk <<= 1) z += __shfl_xor(z, msk);
      inv[r] = __builtin_amdgcn_rcpf(z);  // per-row monotone scale: order-safe
    }
    // --- accumulate mean rows in registers (mean /8 monotone: skip) ---
#pragma unroll
    for (int t2 = 0; t2 < NTILE; ++t2)
#pragma unroll
      for (int r = 0; r < 4; ++r) macc[t2][r] = fmaf(acc[t2][r], inv[r], macc[t2][r]);
  }

  // --- two passes: redistribute 8 rows to LDS, then per-wave top-32 ---
  for (int pass = 0; pass < 2; ++pass) {
    if (pass) __syncthreads();  // protect smean reuse (pass-0 reads done)
    if ((g >> 1) == pass) {
#pragma unroll
      for (int t2 = 0; t2 < NTILE; ++t2)
#pragma unroll
        for (int r = 0; r < 4; ++r)
          smean[((g & 1) * 4 + r) * SMS + w * KW + t2 * 16 + c] = macc[t2][r];
    }
    __syncthreads();

    // wave w: top-32 of local row w (query q0 + pass*8 + w); k = j*64 + l
    float* row = &smean[w * SMS];
    float vals[32];
    float v1 = -1e30f, v2 = -1e30f;
    int i1 = 1 << 30, i2 = 1 << 30;
#pragma unroll
    for (int j = 0; j < 32; ++j) {
      float v = row[j * 64 + l];
      vals[j] = v;
      const int k = j * 64 + l;
      if (v > v1) { v2 = v1; i2 = i1; v1 = v; i1 = k; }
      else if (v > v2) { v2 = v; i2 = k; }
    }
    unsigned rem = 0u;
    int selk = 0;
#pragma unroll 1
    for (int it = 0; it < NE; ++it) {
      float bv = v1;
      int bk = i1;
#pragma unroll
      for (int off = 32; off >= 1; off >>= 1) {
        float ov = __shfl_xor(bv, off);
        int ok = __shfl_xor(bk, off);
        if (ov > bv || (ov == bv && ok < bk)) { bv = ov; bk = ok; }
      }
      if (l == it) selk = bk;
      if (i1 == bk) {  // this lane supplied the winner (k%64==l: unique owner)
        rem |= 1u << (bk >> 6);
        if (i2 != (1 << 30)) {  // promote cached second
          v1 = v2; i1 = i2;
          v2 = -1e30f; i2 = 1 << 30;
        } else {  // rare: rebuild top-2 from masked registers
          v1 = -1e30f; i1 = 1 << 30;
          v2 = -1e30f; i2 = 1 << 30;
#pragma unroll
          for (int j = 0; j < 32; ++j) {
            float v = ((rem >> j) & 1u) ? -1e30f : vals[j];
            const int k = j * 64 + l;
            if (v > v1) { v2 = v1; i2 = i1; v1 = v; i1 = k; }
            else if (v > v2) { v2 = v; i2 = k; }
          }
        }
      }
    }

    // rank-sort the 32 winners by index, write output
    int rank = 0;
#pragma unroll
    for (int j = 0; j < NE; ++j) {
      int o = __shfl(selk, j);
      rank += (o < selk) ? 1 : 0;
    }
    const int qg = q0 + pass * 8 + w;
    if (l < NE) {
      int* o0 = out + (size_t)n * 2 * LSEQ * NE + (size_t)qg * NE;
      int* o1p = o0 + (size_t)LSEQ * NE;
      o0[l] = qg;
      o1p[rank] = selk;
    }
  }
}

// ---------------------------------------------------------------------------
extern "C" void kernel_launch(void* const* d_in, const int* in_sizes, int n_in,
                              void* d_out, int out_size, void* d_ws, size_t ws_size,
                              hipStream_t stream) {
  const float* keys = (const float*)d_in[0];
  const float* query = (const float*)d_in[1];
  const float* Wk = (const float*)d_in[2];
  const float* Wq = (const float*)d_in[3];
  int* out = (int*)d_out;

  const size_t SPLIT = (size_t)NB * HH * LSEQ * DD;  // 4,194,304 elems
  __hip_bfloat16* qs1 = (__hip_bfloat16*)d_ws;
  __hip_bfloat16* qs2 = qs1 + SPLIT;
  __hip_bfloat16* qs3 = qs2 + SPLIT;
  __hip_bfloat16* ks1 = qs3 + SPLIT;
  __hip_bfloat16* ks2 = ks1 + SPLIT;
  __hip_bfloat16* ks3 = ks2 + SPLIT;

  proj_kernel<<<NB * LSEQ, 256, 0, stream>>>(query, Wq, 0.0625f, qs1, qs2, qs3);
  proj_kernel<<<NB * LSEQ, 256, 0, stream>>>(keys, Wk, 1.0f, ks1, ks2, ks3);
  attn_topk_kernel<<<NB * (LSEQ / QT), NTH, 0, stream>>>(qs1, qs2, qs3, ks1, ks2, ks3, out);
}

// Round 5
// 443.842 us; speedup vs baseline: 1.7179x; 1.2546x over previous
//
#include <hip/hip_runtime.h>
#include <hip/hip_bf16.h>

#define NB 8
#define LSEQ 2048
#define HH 8
#define DD 32
#define EE 256
#define NE 32
#define QT 16      // queries per block (one MFMA tile of rows)
#define NWAVE 16
#define NTH 1024
#define KW 128     // keys per wave
#define NTILE 8    // KW / 16
#define SMS 2050   // smean row stride (words)

typedef __attribute__((ext_vector_type(8))) short short8;
typedef __attribute__((ext_vector_type(4))) float f32x4;

// ---------------------------------------------------------------------------
// K1: per-head projection -> 3-way bf16 split (hi/mid/lo ~ 24 mantissa bits).
// out[n][h][l][e] = scale * sum_d x[n][l][h*32+d] * W[e*32+d]
// Q pass uses scale = 1/16 (exact power of two; folds softmax temperature).
// ---------------------------------------------------------------------------
__global__ __launch_bounds__(256) void proj_kernel(const float* __restrict__ x,
                                                   const float* __restrict__ W,
                                                   float scale,
                                                   __hip_bfloat16* __restrict__ o1,
                                                   __hip_bfloat16* __restrict__ o2,
                                                   __hip_bfloat16* __restrict__ o3) {
  const int b = blockIdx.x;  // n*L + l
  __shared__ float xs[EE];
  __shared__ float Ws[DD][DD + 1];
  const int t = threadIdx.x;
  xs[t] = x[(size_t)b * EE + t];
  for (int i = t; i < DD * DD; i += 256) Ws[i / DD][i % DD] = W[i];
  __syncthreads();
  const int h = t / DD, e = t % DD;
  float acc = 0.f;
#pragma unroll
  for (int d = 0; d < DD; ++d) acc = fmaf(xs[h * DD + d], Ws[e][d], acc);
  acc *= scale;
  const int n = b / LSEQ, l = b % LSEQ;
  const size_t oi = (((size_t)n * HH + h) * LSEQ + l) * DD + e;
  __hip_bfloat16 p1 = __float2bfloat16(acc);
  float r1 = acc - __bfloat162float(p1);
  __hip_bfloat16 p2 = __float2bfloat16(r1);
  float r2 = r1 - __bfloat162float(p2);
  __hip_bfloat16 p3 = __float2bfloat16(r2);
  o1[oi] = p1;
  o2[oi] = p2;
  o3[oi] = p3;
}

// ---------------------------------------------------------------------------
// K2: MFMA energy -> per-head softmax (no max-sub; energies/16 bounded ~±3)
//     -> mean accumulated in REGISTERS -> one-pass LDS redistribute -> top-32.
// One block = (n, 16-query tile). 16 waves; wave w owns keys [w*128,(w+1)*128).
// __launch_bounds__(1024, 4): 128-VGPR cap, 4 waves/SIMD (latency hiding).
// Live state ~110 VGPR: macc 32 + acc 32 + Q frags 12 + addr/misc.
// C fragment mapping (verified rounds 2-4): row(query)=g*4+r, col(key)=c.
// ---------------------------------------------------------------------------
__global__ __launch_bounds__(NTH, 4) void attn_topk_kernel(
    const __hip_bfloat16* __restrict__ q1, const __hip_bfloat16* __restrict__ q2,
    const __hip_bfloat16* __restrict__ q3, const __hip_bfloat16* __restrict__ k1,
    const __hip_bfloat16* __restrict__ k2, const __hip_bfloat16* __restrict__ k3,
    int* __restrict__ out) {
  __shared__ float smean[QT * SMS];        // 131 KB: 16 query rows
  __shared__ float wredS[2][QT][NWAVE];    // cross-wave Z partials, dbuf by head parity

  const int t = threadIdx.x;
  const int w = t >> 6, l = t & 63;
  const int g = l >> 4, c = l & 15;  // 16-lane group / lane-in-group
  const int n = blockIdx.x & 7;      // XCD-aligned batch (1024 blocks, %8==0: bijective)
  const int q0 = (blockIdx.x >> 3) * QT;

  float macc[NTILE][4];  // mean-attn accumulator: rows g*4+r, cols w*128+t2*16+c
#pragma unroll
  for (int t2 = 0; t2 < NTILE; ++t2)
#pragma unroll
    for (int r = 0; r < 4; ++r) macc[t2][r] = 0.f;

  for (int h = 0; h < HH; ++h) {
    const size_t hb = ((size_t)n * HH + h) * LSEQ;
    // A fragment (Q): row = c, d-range = g*8..g*8+7
    const size_t qoff = (hb + q0 + c) * DD + (size_t)g * 8;
    const short8 aH = *(const short8*)(q1 + qoff);
    const short8 aM = *(const short8*)(q2 + qoff);
    const short8 aL = *(const short8*)(q3 + qoff);

    f32x4 acc[NTILE];
#pragma unroll
    for (int t2 = 0; t2 < NTILE; ++t2) {
      // B fragment (K): col = c, d-range = g*8..g*8+7
      const size_t koff = (hb + (size_t)w * KW + t2 * 16 + c) * DD + (size_t)g * 8;
      const short8 bH = *(const short8*)(k1 + koff);
      const short8 bM = *(const short8*)(k2 + koff);
      const short8 bL = *(const short8*)(k3 + koff);
      f32x4 a = {0.f, 0.f, 0.f, 0.f};
      a = __builtin_amdgcn_mfma_f32_16x16x32_bf16(aH, bH, a, 0, 0, 0);
      a = __builtin_amdgcn_mfma_f32_16x16x32_bf16(aH, bM, a, 0, 0, 0);
      a = __builtin_amdgcn_mfma_f32_16x16x32_bf16(aM, bH, a, 0, 0, 0);
      a = __builtin_amdgcn_mfma_f32_16x16x32_bf16(aH, bL, a, 0, 0, 0);
      a = __builtin_amdgcn_mfma_f32_16x16x32_bf16(aL, bH, a, 0, 0, 0);
      a = __builtin_amdgcn_mfma_f32_16x16x32_bf16(aM, bM, a, 0, 0, 0);
      acc[t2] = a;
    }

    // --- exp (energies pre-scaled by 1/16 in Q proj; bounded, no max-sub) + Z ---
    float Zl[4] = {0.f, 0.f, 0.f, 0.f};
#pragma unroll
    for (int t2 = 0; t2 < NTILE; ++t2) {
#pragma unroll
      for (int r = 0; r < 4; ++r) {
        float e = __expf(acc[t2][r]);
        acc[t2][r] = e;
        Zl[r] += e;
      }
    }
#pragma unroll
    for (int msk = 1; msk <= 8; msk <<= 1)
#pragma unroll
      for (int r = 0; r < 4; ++r) Zl[r] += __shfl_xor(Zl[r], msk);
    if (c == 0) {
#pragma unroll
      for (int r = 0; r < 4; ++r) wredS[h & 1][g * 4 + r][w] = Zl[r];
    }
    __syncthreads();
    float inv[4];
#pragma unroll
    for (int r = 0; r < 4; ++r) {
      float z = wredS[h & 1][g * 4 + r][c];  // 16 wave partials, c spans them
#pragma unroll
      for (int msk = 1; msk <= 8; msk <<= 1) z += __shfl_xor(z, msk);
      inv[r] = __builtin_amdgcn_rcpf(z);  // per-row monotone scale: order-safe
    }
    // --- accumulate mean rows in registers (mean /8 monotone: skip) ---
#pragma unroll
    for (int t2 = 0; t2 < NTILE; ++t2)
#pragma unroll
      for (int r = 0; r < 4; ++r) macc[t2][r] = fmaf(acc[t2][r], inv[r], macc[t2][r]);
  }

  // --- redistribute all 16 rows to LDS (2-way bank alias max: free) ---
#pragma unroll
  for (int t2 = 0; t2 < NTILE; ++t2)
#pragma unroll
    for (int r = 0; r < 4; ++r)
      smean[(g * 4 + r) * SMS + w * KW + t2 * 16 + c] = macc[t2][r];
  __syncthreads();

  // --- top-32: wave w owns row w (query q0+w); k = j*64 + l ---
  float* row = &smean[w * SMS];
  float vals[32];
  float v1 = -1e30f, v2 = -1e30f;
  int i1 = 1 << 30, i2 = 1 << 30;
#pragma unroll
  for (int j = 0; j < 32; ++j) {
    float v = row[j * 64 + l];
    vals[j] = v;
    const int k = j * 64 + l;
    if (v > v1) { v2 = v1; i2 = i1; v1 = v; i1 = k; }
    else if (v > v2) { v2 = v; i2 = k; }
  }
  unsigned rem = 0u;
  int selk = 0;
#pragma unroll 1
  for (int it = 0; it < NE; ++it) {
    float bv = v1;
    int bk = i1;
#pragma unroll
    for (int off = 32; off >= 1; off >>= 1) {
      float ov = __shfl_xor(bv, off);
      int ok = __shfl_xor(bk, off);
      if (ov > bv || (ov == bv && ok < bk)) { bv = ov; bk = ok; }
    }
    if (l == it) selk = bk;
    if (i1 == bk) {  // this lane supplied the winner (k%64==l: unique owner)
      rem |= 1u << (bk >> 6);
      if (i2 != (1 << 30)) {  // promote cached second
        v1 = v2; i1 = i2;
        v2 = -1e30f; i2 = 1 << 30;
      } else {  // rare: rebuild top-2 from masked registers
        v1 = -1e30f; i1 = 1 << 30;
        v2 = -1e30f; i2 = 1 << 30;
#pragma unroll
        for (int j = 0; j < 32; ++j) {
          float v = ((rem >> j) & 1u) ? -1e30f : vals[j];
          const int k = j * 64 + l;
          if (v > v1) { v2 = v1; i2 = i1; v1 = v; i1 = k; }
          else if (v > v2) { v2 = v; i2 = k; }
        }
      }
    }
  }

  // --- rank-sort the 32 winners by index, write output ---
  int rank = 0;
#pragma unroll
  for (int j = 0; j < NE; ++j) {
    int o = __shfl(selk, j);
    rank += (o < selk) ? 1 : 0;
  }
  const int qg = q0 + w;
  if (l < NE) {
    int* o0 = out + (size_t)n * 2 * LSEQ * NE + (size_t)qg * NE;
    int* o1p = o0 + (size_t)LSEQ * NE;
    o0[l] = qg;
    o1p[rank] = selk;
  }
}

// ---------------------------------------------------------------------------
extern "C" void kernel_launch(void* const* d_in, const int* in_sizes, int n_in,
                              void* d_out, int out_size, void* d_ws, size_t ws_size,
                              hipStream_t stream) {
  const float* keys = (const float*)d_in[0];
  const float* query = (const float*)d_in[1];
  const float* Wk = (const float*)d_in[2];
  const float* Wq = (const float*)d_in[3];
  int* out = (int*)d_out;

  const size_t SPLIT = (size_t)NB * HH * LSEQ * DD;  // 4,194,304 elems
  __hip_bfloat16* qs1 = (__hip_bfloat16*)d_ws;
  __hip_bfloat16* qs2 = qs1 + SPLIT;
  __hip_bfloat16* qs3 = qs2 + SPLIT;
  __hip_bfloat16* ks1 = qs3 + SPLIT;
  __hip_bfloat16* ks2 = ks1 + SPLIT;
  __hip_bfloat16* ks3 = ks2 + SPLIT;

  proj_kernel<<<NB * LSEQ, 256, 0, stream>>>(query, Wq, 0.0625f, qs1, qs2, qs3);
  proj_kernel<<<NB * LSEQ, 256, 0, stream>>>(keys, Wk, 1.0f, ks1, ks2, ks3);
  attn_topk_kernel<<<NB * (LSEQ / QT), NTH, 0, stream>>>(qs1, qs2, qs3, ks1, ks2, ks3, out);
}